// Round 12
// baseline (290.148 us; speedup 1.0000x reference)
//
#include <hip/hip_runtime.h>
#include <math.h>

#define ACT_RELU 0
#define ACT_LSM  1
#define BSH 8        // bucket = 256 consecutive dst nodes
#define MAXNB 512    // max buckets supported by the scan / LDS hist

typedef __attribute__((ext_vector_type(8))) short bf16x8;   // 8 bf16 (4 VGPRs)
typedef __attribute__((ext_vector_type(4))) float f32x4;
typedef __attribute__((ext_vector_type(2))) float f32x2;
typedef __attribute__((ext_vector_type(4))) unsigned int u32x4;
typedef __attribute__((ext_vector_type(2))) unsigned int u32x2;

// bf16 helpers (OCP bf16 = top 16 bits of f32; RNE pack)
__device__ __forceinline__ unsigned f2bf(float f) {
  unsigned u = __float_as_uint(f);
  u += 0x7fffu + ((u >> 16) & 1u);
  return u >> 16;
}
// fp8 e4m3 (OCP on gfx950) via HW converts; word-select must be a literal
template <bool HI>
__device__ __forceinline__ f32x2 f8cvt(unsigned w) {
  return __builtin_amdgcn_cvt_pk_f32_fp8((int)w, HI);
}
__device__ __forceinline__ unsigned char f2f8(float v) {
  return (unsigned char)(__builtin_amdgcn_cvt_pk_fp8_f32(v, v, 0, false) & 0xff);
}

// ---------------- tiny zero (replaces in-graph hipMemsetAsync) ----------------
__global__ void k_zero(int* __restrict__ p, int n) {
  int i = blockIdx.x * 256 + threadIdx.x;
  if (i < n) p[i] = 0;
}

// ---------------- CSR build (bucketed, atomic-light) ----------------
__global__ void k_histB(const int* __restrict__ dst, int* __restrict__ bucket_cnt,
                        int E, int NB) {
  __shared__ int cntL[MAXNB];
  int t = threadIdx.x;
  for (int b = t; b < NB; b += 256) cntL[b] = 0;
  __syncthreads();
  int e0 = blockIdx.x * 4096;
  int e1 = min(e0 + 4096, E);
  for (int i = e0 + t; i < e1; i += 256) atomicAdd(&cntL[dst[i] >> BSH], 1);
  __syncthreads();
  for (int b = t; b < NB; b += 256)
    if (cntL[b]) atomicAdd(&bucket_cnt[b], cntL[b]);
}

__global__ void k_bscan(const int* __restrict__ bucket_cnt, int* __restrict__ bucket_base,
                        int* __restrict__ bucket_cursor, int NB) {
  __shared__ int sm[MAXNB];
  int t = threadIdx.x;  // 512 threads
  sm[t] = (t < NB) ? bucket_cnt[t] : 0;
  __syncthreads();
  for (int off = 1; off < MAXNB; off <<= 1) {
    int x = (t >= off) ? sm[t - off] : 0;
    __syncthreads();
    sm[t] += x;
    __syncthreads();
  }
  int ex = (t == 0) ? 0 : sm[t - 1];
  if (t <= NB) bucket_base[t] = ex;
  if (t < NB) bucket_cursor[t] = ex;
}

__global__ void k_partition(const int* __restrict__ src, const int* __restrict__ dst,
                            int* __restrict__ bucket_cursor, int2* __restrict__ tmp,
                            int E, int NB) {
  __shared__ int cntL[MAXNB];
  __shared__ int baseL[MAXNB];
  int t = threadIdx.x;
  for (int b = t; b < NB; b += 256) cntL[b] = 0;
  __syncthreads();
  int e0 = blockIdx.x * 4096;
  int e1 = min(e0 + 4096, E);
  for (int i = e0 + t; i < e1; i += 256) atomicAdd(&cntL[dst[i] >> BSH], 1);
  __syncthreads();
  for (int b = t; b < NB; b += 256) {
    int c = cntL[b];
    baseL[b] = c ? atomicAdd(&bucket_cursor[b], c) : 0;
    cntL[b] = 0;  // reuse as local cursor
  }
  __syncthreads();
  for (int i = e0 + t; i < e1; i += 256) {
    int s = src[i], d = dst[i];  // second dst read is L2-hot
    int b = d >> BSH;
    int r = atomicAdd(&cntL[b], 1);
    tmp[baseL[b] + r] = make_int2(s, d);
  }
}

__global__ void __launch_bounds__(256) k_bmake(const int2* __restrict__ tmp,
                                               const int* __restrict__ bucket_base,
                                               int* __restrict__ row_ptr,
                                               int* __restrict__ edge_src,
                                               int N, int E, int NB) {
  __shared__ int cntL[256];
  __shared__ int scanL[256];
  int b = blockIdx.x;
  int t = threadIdx.x;
  int e0 = bucket_base[b], e1 = bucket_base[b + 1];
  cntL[t] = 0;
  __syncthreads();
  for (int i = e0 + t; i < e1; i += 256) atomicAdd(&cntL[tmp[i].y & 255], 1);
  __syncthreads();
  int v = cntL[t];
  scanL[t] = v;
  __syncthreads();
  for (int off = 1; off < 256; off <<= 1) {
    int x = (t >= off) ? scanL[t - off] : 0;
    __syncthreads();
    scanL[t] += x;
    __syncthreads();
  }
  int exc = scanL[t] - v;
  int node = (b << BSH) + t;
  if (node < N) row_ptr[node] = e0 + exc;
  if (b == NB - 1 && t == 0) row_ptr[N] = E;
  __syncthreads();
  cntL[t] = e0 + exc;  // reuse as cursor
  __syncthreads();
  for (int i = e0 + t; i < e1; i += 256) {
    int2 e = tmp[i];
    int p = atomicAdd(&cntL[e.y & 255], 1);  // LDS atomic
    edge_src[p] = e.x;
  }
}

// ---------------- fallback path (NB > MAXNB) ----------------
__global__ void k_hist(const int* __restrict__ dst, int* __restrict__ cnt, int E) {
  int i = blockIdx.x * blockDim.x + threadIdx.x;
  if (i < E) atomicAdd(&cnt[dst[i]], 1);
}

__global__ void k_scan_part(const int* __restrict__ cnt, int* __restrict__ bsum, int M) {
  __shared__ int sm[256];
  int t = threadIdx.x;
  int base = blockIdx.x * 2048 + t * 8;
  int s = 0;
#pragma unroll
  for (int j = 0; j < 8; ++j) { int i = base + j; if (i < M) s += cnt[i]; }
  sm[t] = s;
  __syncthreads();
  for (int off = 128; off > 0; off >>= 1) {
    if (t < off) sm[t] += sm[t + off];
    __syncthreads();
  }
  if (t == 0) bsum[blockIdx.x] = sm[0];
}

__global__ void k_scan_mid(const int* __restrict__ bsum, int* __restrict__ boff, int nb) {
  int l = threadIdx.x;
  int v = (l < nb) ? bsum[l] : 0;
  int inc = v;
  for (int off = 1; off < 64; off <<= 1) {
    int u = __shfl_up(inc, off);
    if (l >= off) inc += u;
  }
  if (l < nb) boff[l] = inc - v;
}

__global__ void k_scan_final(const int* __restrict__ cnt, const int* __restrict__ boff,
                             int* __restrict__ row_ptr, int* __restrict__ cursor, int M) {
  __shared__ int sm[256];
  int t = threadIdx.x;
  int base = blockIdx.x * 2048 + t * 8;
  int v[8];
  int s = 0;
#pragma unroll
  for (int j = 0; j < 8; ++j) { int i = base + j; v[j] = (i < M) ? cnt[i] : 0; s += v[j]; }
  sm[t] = s;
  __syncthreads();
  for (int off = 1; off < 256; off <<= 1) {
    int x = (t >= off) ? sm[t - off] : 0;
    __syncthreads();
    sm[t] += x;
    __syncthreads();
  }
  int run = boff[blockIdx.x] + sm[t] - s;
#pragma unroll
  for (int j = 0; j < 8; ++j) {
    int i = base + j;
    if (i < M) { row_ptr[i] = run; cursor[i] = run; }
    run += v[j];
  }
}

__global__ void k_fill(const int* __restrict__ src, const int* __restrict__ dst,
                       int* __restrict__ cursor, int* __restrict__ edge_src, int E) {
  int i = blockIdx.x * blockDim.x + threadIdx.x;
  if (i < E) {
    int d = dst[i];
    int p = atomicAdd(&cursor[d], 1);
    edge_src[p] = src[i];
  }
}

// ---------------- cast f32 -> bf16 + fp8 planes (8 elems/thread) ----------------
// fp8 stored as two planes: x8[p][node][32], p = dim>>5. Each plane = N*32 B.
__global__ void __launch_bounds__(256) k_cast(const float* __restrict__ x,
                                              unsigned short* __restrict__ xb,
                                              unsigned char* __restrict__ x8, int node_n,
                                              int n) {
  int i = blockIdx.x * 256 + threadIdx.x;  // unit of 8 elements
  if (i * 8 < n) {
    const f32x4* p = (const f32x4*)(x + (size_t)i * 8);
    f32x4 a = __builtin_nontemporal_load(p);
    f32x4 b = __builtin_nontemporal_load(p + 1);
    u32x4 w;
    w.x = f2bf(a.x) | (f2bf(a.y) << 16);
    w.y = f2bf(a.z) | (f2bf(a.w) << 16);
    w.z = f2bf(b.x) | (f2bf(b.y) << 16);
    w.w = f2bf(b.z) | (f2bf(b.w) << 16);
    __builtin_nontemporal_store(w, (u32x4*)(xb + (size_t)i * 8));
    u32x2 q;
    q.x = (unsigned)__builtin_amdgcn_cvt_pk_fp8_f32(a.x, a.y, 0, false);
    q.x = (unsigned)__builtin_amdgcn_cvt_pk_fp8_f32(a.z, a.w, (int)q.x, true);
    q.y = (unsigned)__builtin_amdgcn_cvt_pk_fp8_f32(b.x, b.y, 0, false);
    q.y = (unsigned)__builtin_amdgcn_cvt_pk_fp8_f32(b.z, b.w, (int)q.y, true);
    int node = i >> 3;
    int d0 = (i & 7) * 8;                 // 0..56
    int plane = d0 >> 5;                  // 0 or 1
    int off = d0 & 31;                    // 0,8,16,24
    __builtin_nontemporal_store(q,
        (u32x2*)(x8 + (size_t)plane * node_n * 32 + (size_t)node * 32 + off));
  }
}

// ---------------- fused SAGE layer: out = act([mean_agg(h), h] @ [Wl; Wr] + b) ----------------
// 4 waves/block, 16 rows/wave. Phase A: TWO dim-half passes over fp8 planes
// (each plane N*32 B = L2-resident); 4 lanes/node x 16 nodes/wave, 8 edges in
// flight, f32 accumulate. All streaming traffic is non-temporal so the fp8
// plane stays L2-hot. Phase B: MFMA K=128.
// mfma_f32_16x16x32_bf16: A row = lane&15, k = (lane>>4)*8+j; C/D col = lane&15,
// row = (lane>>4)*4 + reg  [verified R6-R10].
#define MPAD 80  // meanL row pad (ushorts)

template <int DOUT, int ACT>
__global__ void __launch_bounds__(256) k_layer(const unsigned short* __restrict__ h,
                                               const unsigned char* __restrict__ h8,
                                               const int* __restrict__ row_ptr,
                                               const int* __restrict__ edge_src,
                                               const float* __restrict__ Wl,
                                               const float* __restrict__ Wr,
                                               const float* __restrict__ bias,
                                               void* __restrict__ outv,
                                               unsigned char* __restrict__ out8, int n) {
  constexpr int NT = (DOUT + 15) / 16;  // 4 (d=64) or 3 (d=40)
  constexpr int PADN = NT * 16;
  __shared__ unsigned short Wlds[128 * PADN];
  __shared__ unsigned short meanL[4][16 * MPAD];
  int t = threadIdx.x;

  // stage W in fragment-linear order over the LDS index (conflict-free ds_write)
  for (int fi = t; fi < 128 * PADN; fi += 256) {
    int k7 = fi & 7;
    int kb = (fi >> 3) & 3;
    int c16 = (fi >> 5) & 15;
    int rest = fi >> 9;          // kb5 * NT + nt
    int nt = rest % NT;
    int kb5 = rest / NT;
    int k = kb5 * 32 + kb * 8 + k7;
    int nn = nt * 16 + c16;
    float v = 0.f;
    if (nn < DOUT) v = (k < 64) ? Wl[k * DOUT + nn] : Wr[(k - 64) * DOUT + nn];
    Wlds[fi] = (unsigned short)f2bf(v);
  }

  int w = t >> 6, lane = t & 63;
  int r0 = (blockIdx.x * 4 + w) * 16;  // wave's 16 rows
  int node = lane >> 2;                // 16 nodes per wave
  int g = lane & 3;                    // dim-group of 8 fp8 (8B) within a 32B half
  int nb = lane & ~3;                  // first lane of this node's group
  int i = r0 + node;

  int rp0 = 0, rp1 = 0, deg = 0;
  float scale = 0.f;
  if (i < n) {
    rp0 = row_ptr[i];
    rp1 = row_ptr[i + 1];
    deg = rp1 - rp0;
    scale = (deg > 0) ? (1.0f / (float)deg) : 0.f;
  }

  // ---- phase A: two dim-half passes over the L2-resident fp8 plane ----
  for (int p = 0; p < 2; ++p) {
    const unsigned char* hp = h8 + (size_t)p * n * 32;
    float a[8];
#pragma unroll
    for (int c = 0; c < 8; ++c) a[c] = 0.f;
    for (int base = 0; base < deg; base += 8) {
      int ia = rp0 + base + g;
      int ib = ia + 4;
      int sva = (ia < rp1) ? __builtin_nontemporal_load(&edge_src[ia]) : 0;
      int svb = (ib < rp1) ? __builtin_nontemporal_load(&edge_src[ib]) : 0;
      int cnt = min(8, deg - base);
      u32x2 v0, v1, v2, v3, v4, v5, v6, v7;
#pragma unroll
      for (int e = 0; e < 8; ++e) {
        int s = __shfl((e < 4) ? sva : svb, nb | (e & 3));
        const u32x2* ptr = (const u32x2*)(hp + (size_t)s * 32) + g;
        if (e == 0 && e < cnt) v0 = *ptr;
        if (e == 1 && e < cnt) v1 = *ptr;
        if (e == 2 && e < cnt) v2 = *ptr;
        if (e == 3 && e < cnt) v3 = *ptr;
        if (e == 4 && e < cnt) v4 = *ptr;
        if (e == 5 && e < cnt) v5 = *ptr;
        if (e == 6 && e < cnt) v6 = *ptr;
        if (e == 7 && e < cnt) v7 = *ptr;
      }
#define ACCUM(vv, ee)                                                    \
      if ((ee) < cnt) {                                                  \
        f32x2 p0 = f8cvt<false>(vv.x), p1 = f8cvt<true>(vv.x);           \
        f32x2 p2 = f8cvt<false>(vv.y), p3 = f8cvt<true>(vv.y);           \
        a[0] += p0.x; a[1] += p0.y; a[2] += p1.x; a[3] += p1.y;          \
        a[4] += p2.x; a[5] += p2.y; a[6] += p3.x; a[7] += p3.y;          \
      }
      ACCUM(v0, 0) ACCUM(v1, 1) ACCUM(v2, 2) ACCUM(v3, 3)
      ACCUM(v4, 4) ACCUM(v5, 5) ACCUM(v6, 6) ACCUM(v7, 7)
#undef ACCUM
    }
    u32x4 wv;
    wv.x = f2bf(a[0] * scale) | (f2bf(a[1] * scale) << 16);
    wv.y = f2bf(a[2] * scale) | (f2bf(a[3] * scale) << 16);
    wv.z = f2bf(a[4] * scale) | (f2bf(a[5] * scale) << 16);
    wv.w = f2bf(a[6] * scale) | (f2bf(a[7] * scale) << 16);
    *(u32x4*)&meanL[w][node * MPAD + p * 32 + g * 8] = wv;
  }
  __syncthreads();  // W + all mean tiles staged

  // ---- phase B: MFMA ----
  int c = lane & 15;   // A row / C-D col
  int kb = lane >> 4;  // k-block of 8
  bf16x8 bf[4][NT];
#pragma unroll
  for (int s = 0; s < 4; ++s)
#pragma unroll
    for (int nt = 0; nt < NT; ++nt)
      bf[s][nt] = *(const bf16x8*)&Wlds[(((s * NT + nt) * 16 + c) * 4 + kb) * 8];

  bf16x8 af[4];
  af[0] = *(const bf16x8*)&meanL[w][c * MPAD + kb * 8];        // mean, k 0..31
  af[1] = *(const bf16x8*)&meanL[w][c * MPAD + 32 + kb * 8];   // mean, k 32..63
  int row = r0 + c;
  if (row >= n) row = n - 1;  // clamp loads; stores guarded
  size_t rb = (size_t)row * 64 + kb * 8;
  af[2] = __builtin_nontemporal_load((const bf16x8*)(h + rb));       // own row, k 0..31
  af[3] = __builtin_nontemporal_load((const bf16x8*)(h + rb + 32));  // own row, k 32..63

  f32x4 acc[NT];
#pragma unroll
  for (int nt = 0; nt < NT; ++nt) acc[nt] = (f32x4){0.f, 0.f, 0.f, 0.f};
#pragma unroll
  for (int s = 0; s < 4; ++s)
#pragma unroll
    for (int nt = 0; nt < NT; ++nt)
      acc[nt] = __builtin_amdgcn_mfma_f32_16x16x32_bf16(af[s], bf[s][nt], acc[nt], 0, 0, 0);

  int rbase = r0 + kb * 4;
  if (ACT == ACT_RELU) {
    unsigned short* out = (unsigned short*)outv;
#pragma unroll
    for (int nt = 0; nt < NT; ++nt) {
      float bval = bias[nt * 16 + c];
      int col = nt * 16 + c;
      int plane = col >> 5, colp = col & 31;
#pragma unroll
      for (int r = 0; r < 4; ++r) {
        int R = rbase + r;
        if (R < n) {
          float v = fmaxf(acc[nt][r] + bval, 0.f);
          __builtin_nontemporal_store((unsigned short)f2bf(v),
                                      out + (size_t)R * DOUT + col);
          __builtin_nontemporal_store(f2f8(v),
                                      out8 + ((size_t)plane * n + R) * 32 + colp);
        }
      }
    }
  } else {
    float* out = (float*)outv;
    float bv[NT];
#pragma unroll
    for (int nt = 0; nt < NT; ++nt) bv[nt] = ((nt * 16 + c) < DOUT) ? bias[nt * 16 + c] : 0.f;
#pragma unroll
    for (int r = 0; r < 4; ++r) {
      int R = rbase + r;
      float v[NT];
      float m = -INFINITY;
#pragma unroll
      for (int nt = 0; nt < NT; ++nt) {
        bool valid = (nt * 16 + c) < DOUT;
        v[nt] = valid ? (acc[nt][r] + bv[nt]) : -INFINITY;
        m = fmaxf(m, v[nt]);
      }
#pragma unroll
      for (int off = 1; off < 16; off <<= 1) m = fmaxf(m, __shfl_xor(m, off));
      float es = 0.f;
#pragma unroll
      for (int nt = 0; nt < NT; ++nt)
        if ((nt * 16 + c) < DOUT) es += expf(v[nt] - m);
#pragma unroll
      for (int off = 1; off < 16; off <<= 1) es += __shfl_xor(es, off);
      float lse = logf(es);
      if (R < n) {
#pragma unroll
        for (int nt = 0; nt < NT; ++nt)
          if ((nt * 16 + c) < DOUT)
            __builtin_nontemporal_store(v[nt] - m - lse,
                                        out + (size_t)R * DOUT + nt * 16 + c);
      }
    }
  }
}

extern "C" void kernel_launch(void* const* d_in, const int* in_sizes, int n_in,
                              void* d_out, int out_size, void* d_ws, size_t ws_size,
                              hipStream_t stream) {
  const float* x   = (const float*)d_in[0];
  const int*   ei  = (const int*)d_in[1];
  const float* Wl0 = (const float*)d_in[2];
  const float* bl0 = (const float*)d_in[3];
  const float* Wr0 = (const float*)d_in[4];
  const float* Wl1 = (const float*)d_in[5];
  const float* bl1 = (const float*)d_in[6];
  const float* Wr1 = (const float*)d_in[7];
  const float* Wl2 = (const float*)d_in[8];
  const float* bl2 = (const float*)d_in[9];
  const float* Wr2 = (const float*)d_in[10];
  float* out = (float*)d_out;

  int N = in_sizes[0] / 64;
  int E = in_sizes[1] / 2;
  int M = N + 1;
  int NB = (N + 255) >> BSH;  // 391 for N=100000
  const int* src = ei;
  const int* dst = ei + E;

  char* p = (char*)d_ws;
  auto alloc = [&](size_t bytes) {
    char* r = p;
    p += (bytes + 255) & ~(size_t)255;
    return r;
  };
  int* cnt      = (int*)alloc((size_t)M * 4);
  int* row_ptr  = (int*)alloc((size_t)M * 4);
  int* cursor   = (int*)alloc((size_t)M * 4);
  int* bsum     = (int*)alloc(256 * 4);
  int* boff     = (int*)alloc(256 * 4);
  int* bk_cnt   = (int*)alloc((MAXNB + 1) * 4);
  int* bk_base  = (int*)alloc((MAXNB + 1) * 4);
  int* bk_cur   = (int*)alloc((MAXNB + 1) * 4);
  int* edge_src = (int*)alloc((size_t)E * 4);
  // R1: int2 tmp during CSR build, then xb (bf16 x), then hbB (layer-1 out, bf16)
  size_t szR1 = (size_t)E * 8 > (size_t)N * 128 ? (size_t)E * 8 : (size_t)N * 128;
  char* R1              = alloc(szR1);
  unsigned short* hbA   = (unsigned short*)alloc((size_t)N * 128);  // hidden (bf16)
  unsigned char*  P8A   = (unsigned char*)alloc((size_t)N * 64);    // fp8 planes: x8 / h8B
  unsigned char*  P8B   = (unsigned char*)alloc((size_t)N * 64);    // fp8 planes: h8A
  if ((size_t)(p - (char*)d_ws) > ws_size) return;  // ws too small: fail loudly

  bool bucketed = (NB <= MAXNB);
  int eb4 = (E + 4095) / 4096;

  if (bucketed) {
    k_zero<<<(MAXNB + 256) / 256, 256, 0, stream>>>(bk_cnt, MAXNB + 1);
    k_histB<<<eb4, 256, 0, stream>>>(dst, bk_cnt, E, NB);
    k_bscan<<<1, MAXNB, 0, stream>>>(bk_cnt, bk_base, bk_cur, NB);
    k_partition<<<eb4, 256, 0, stream>>>(src, dst, bk_cur, (int2*)R1, E, NB);
    k_bmake<<<NB, 256, 0, stream>>>((const int2*)R1, bk_base, row_ptr, edge_src, N, E, NB);
  } else {
    k_zero<<<(M + 255) / 256, 256, 0, stream>>>(cnt, M);
    k_hist<<<(E + 255) / 256, 256, 0, stream>>>(dst, cnt, E);
    int nb = (M + 2047) / 2048;
    k_scan_part<<<nb, 256, 0, stream>>>(cnt, bsum, M);
    k_scan_mid<<<1, 64, 0, stream>>>(bsum, boff, nb);
    k_scan_final<<<nb, 256, 0, stream>>>(cnt, boff, row_ptr, cursor, M);
    k_fill<<<(E + 255) / 256, 256, 0, stream>>>(src, dst, cursor, edge_src, E);
  }

  unsigned short* xb  = (unsigned short*)R1;  // reuses tmp region (dead after k_bmake)
  unsigned short* hbB = (unsigned short*)R1;  // reused again (xb dead after layer 0)
  unsigned char*  x8  = P8A;                  // fp8 x (2 planes)
  unsigned char*  h8A = P8B;                  // fp8 hidden A
  unsigned char*  h8B = P8A;                  // fp8 hidden B (x8 dead after layer 0)

  int cb = (N * 64 / 8 + 255) / 256;
  int gb = (N + 63) / 64;

  k_cast<<<cb, 256, 0, stream>>>(x, xb, x8, N, N * 64);
  // layer 0: hbA = relu([mean_agg(x), x] @ [Wl0; Wr0] + bl0)   (gather fp8 planes)
  k_layer<64, ACT_RELU><<<gb, 256, 0, stream>>>(xb, x8, row_ptr, edge_src, Wl0, Wr0, bl0, hbA, h8A, N);
  // layer 1: hbB = relu([mean_agg(hbA), hbA] @ [Wl1; Wr1] + bl1)
  k_layer<64, ACT_RELU><<<gb, 256, 0, stream>>>(hbA, h8A, row_ptr, edge_src, Wl1, Wr1, bl1, hbB, h8B, N);
  // layer 2: out = log_softmax([mean_agg(hbB), hbB] @ [Wl2; Wr2] + bl2)
  k_layer<40, ACT_LSM><<<gb, 256, 0, stream>>>(hbB, h8B, row_ptr, edge_src, Wl2, Wr2, bl2, out, nullptr, N);
}

// Round 13
// 196.183 us; speedup vs baseline: 1.4790x; 1.4790x over previous
//
#include <hip/hip_runtime.h>
#include <math.h>

#define ACT_RELU 0
#define ACT_LSM  1
#define BSH 8        // bucket = 256 consecutive dst nodes
#define MAXNB 512    // max buckets supported by the scan / LDS hist
#define MPAD 80      // meanL row pad (ushorts)

typedef __attribute__((ext_vector_type(8))) short bf16x8;   // 8 bf16 (4 VGPRs)
typedef __attribute__((ext_vector_type(4))) float f32x4;

// bf16 helpers (OCP bf16 = top 16 bits of f32; RNE pack)
__device__ __forceinline__ unsigned f2bf(float f) {
  unsigned u = __float_as_uint(f);
  u += 0x7fffu + ((u >> 16) & 1u);
  return u >> 16;
}
__device__ __forceinline__ float bflo(unsigned u) { return __uint_as_float(u << 16); }
__device__ __forceinline__ float bfhi(unsigned u) { return __uint_as_float(u & 0xffff0000u); }

// ---------------- tiny zero (replaces in-graph hipMemsetAsync) ----------------
__global__ void k_zero(int* __restrict__ p, int n) {
  int i = blockIdx.x * 256 + threadIdx.x;
  if (i < n) p[i] = 0;
}

// ---------------- CSR build (bucketed, atomic-light) ----------------
__global__ void k_histB(const int* __restrict__ dst, int* __restrict__ bucket_cnt,
                        int E, int NB) {
  __shared__ int cntL[MAXNB];
  int t = threadIdx.x;
  for (int b = t; b < NB; b += 256) cntL[b] = 0;
  __syncthreads();
  int e0 = blockIdx.x * 4096;
  int e1 = min(e0 + 4096, E);
  for (int i = e0 + t; i < e1; i += 256) atomicAdd(&cntL[dst[i] >> BSH], 1);
  __syncthreads();
  for (int b = t; b < NB; b += 256)
    if (cntL[b]) atomicAdd(&bucket_cnt[b], cntL[b]);
}

__global__ void k_bscan(const int* __restrict__ bucket_cnt, int* __restrict__ bucket_base,
                        int* __restrict__ bucket_cursor, int NB) {
  __shared__ int sm[MAXNB];
  int t = threadIdx.x;  // 512 threads
  sm[t] = (t < NB) ? bucket_cnt[t] : 0;
  __syncthreads();
  for (int off = 1; off < MAXNB; off <<= 1) {
    int x = (t >= off) ? sm[t - off] : 0;
    __syncthreads();
    sm[t] += x;
    __syncthreads();
  }
  int ex = (t == 0) ? 0 : sm[t - 1];
  if (t <= NB) bucket_base[t] = ex;
  if (t < NB) bucket_cursor[t] = ex;
}

__global__ void k_partition(const int* __restrict__ src, const int* __restrict__ dst,
                            int* __restrict__ bucket_cursor, int2* __restrict__ tmp,
                            int E, int NB) {
  __shared__ int cntL[MAXNB];
  __shared__ int baseL[MAXNB];
  int t = threadIdx.x;
  for (int b = t; b < NB; b += 256) cntL[b] = 0;
  __syncthreads();
  int e0 = blockIdx.x * 4096;
  int e1 = min(e0 + 4096, E);
  for (int i = e0 + t; i < e1; i += 256) atomicAdd(&cntL[dst[i] >> BSH], 1);
  __syncthreads();
  for (int b = t; b < NB; b += 256) {
    int c = cntL[b];
    baseL[b] = c ? atomicAdd(&bucket_cursor[b], c) : 0;
    cntL[b] = 0;  // reuse as local cursor
  }
  __syncthreads();
  for (int i = e0 + t; i < e1; i += 256) {
    int s = src[i], d = dst[i];  // second dst read is L2-hot
    int b = d >> BSH;
    int r = atomicAdd(&cntL[b], 1);
    tmp[baseL[b] + r] = make_int2(s, d);
  }
}

__global__ void __launch_bounds__(256) k_bmake(const int2* __restrict__ tmp,
                                               const int* __restrict__ bucket_base,
                                               int* __restrict__ row_ptr,
                                               int* __restrict__ edge_src,
                                               int N, int E, int NB) {
  __shared__ int cntL[256];
  __shared__ int scanL[256];
  int b = blockIdx.x;
  int t = threadIdx.x;
  int e0 = bucket_base[b], e1 = bucket_base[b + 1];
  cntL[t] = 0;
  __syncthreads();
  for (int i = e0 + t; i < e1; i += 256) atomicAdd(&cntL[tmp[i].y & 255], 1);
  __syncthreads();
  int v = cntL[t];
  scanL[t] = v;
  __syncthreads();
  for (int off = 1; off < 256; off <<= 1) {
    int x = (t >= off) ? scanL[t - off] : 0;
    __syncthreads();
    scanL[t] += x;
    __syncthreads();
  }
  int exc = scanL[t] - v;
  int node = (b << BSH) + t;
  if (node < N) row_ptr[node] = e0 + exc;
  if (b == NB - 1 && t == 0) row_ptr[N] = E;
  __syncthreads();
  cntL[t] = e0 + exc;  // reuse as cursor
  __syncthreads();
  for (int i = e0 + t; i < e1; i += 256) {
    int2 e = tmp[i];
    int p = atomicAdd(&cntL[e.y & 255], 1);  // LDS atomic
    edge_src[p] = e.x;
  }
}

// ---------------- fallback path (NB > MAXNB) ----------------
__global__ void k_hist(const int* __restrict__ dst, int* __restrict__ cnt, int E) {
  int i = blockIdx.x * blockDim.x + threadIdx.x;
  if (i < E) atomicAdd(&cnt[dst[i]], 1);
}

__global__ void k_scan_part(const int* __restrict__ cnt, int* __restrict__ bsum, int M) {
  __shared__ int sm[256];
  int t = threadIdx.x;
  int base = blockIdx.x * 2048 + t * 8;
  int s = 0;
#pragma unroll
  for (int j = 0; j < 8; ++j) { int i = base + j; if (i < M) s += cnt[i]; }
  sm[t] = s;
  __syncthreads();
  for (int off = 128; off > 0; off >>= 1) {
    if (t < off) sm[t] += sm[t + off];
    __syncthreads();
  }
  if (t == 0) bsum[blockIdx.x] = sm[0];
}

__global__ void k_scan_mid(const int* __restrict__ bsum, int* __restrict__ boff, int nb) {
  int l = threadIdx.x;
  int v = (l < nb) ? bsum[l] : 0;
  int inc = v;
  for (int off = 1; off < 64; off <<= 1) {
    int u = __shfl_up(inc, off);
    if (l >= off) inc += u;
  }
  if (l < nb) boff[l] = inc - v;
}

__global__ void k_scan_final(const int* __restrict__ cnt, const int* __restrict__ boff,
                             int* __restrict__ row_ptr, int* __restrict__ cursor, int M) {
  __shared__ int sm[256];
  int t = threadIdx.x;
  int base = blockIdx.x * 2048 + t * 8;
  int v[8];
  int s = 0;
#pragma unroll
  for (int j = 0; j < 8; ++j) { int i = base + j; v[j] = (i < M) ? cnt[i] : 0; s += v[j]; }
  sm[t] = s;
  __syncthreads();
  for (int off = 1; off < 256; off <<= 1) {
    int x = (t >= off) ? sm[t - off] : 0;
    __syncthreads();
    sm[t] += x;
    __syncthreads();
  }
  int run = boff[blockIdx.x] + sm[t] - s;
#pragma unroll
  for (int j = 0; j < 8; ++j) {
    int i = base + j;
    if (i < M) { row_ptr[i] = run; cursor[i] = run; }
    run += v[j];
  }
}

__global__ void k_fill(const int* __restrict__ src, const int* __restrict__ dst,
                       int* __restrict__ cursor, int* __restrict__ edge_src, int E) {
  int i = blockIdx.x * blockDim.x + threadIdx.x;
  if (i < E) {
    int d = dst[i];
    int p = atomicAdd(&cursor[d], 1);
    edge_src[p] = src[i];
  }
}

// ---------------- cast f32 -> bf16 (8 elems/thread) ----------------
__global__ void __launch_bounds__(256) k_cast(const float* __restrict__ x,
                                              unsigned short* __restrict__ xb, int n) {
  int i = blockIdx.x * 256 + threadIdx.x;  // unit of 8 elements
  if (i * 8 < n) {
    const float4* p = (const float4*)(x + (size_t)i * 8);
    float4 a = p[0], b = p[1];
    uint4 w;
    w.x = f2bf(a.x) | (f2bf(a.y) << 16);
    w.y = f2bf(a.z) | (f2bf(a.w) << 16);
    w.z = f2bf(b.x) | (f2bf(b.y) << 16);
    w.w = f2bf(b.z) | (f2bf(b.w) << 16);
    *(uint4*)(xb + (size_t)i * 8) = w;
  }
}

// ---------------- pre-pack W into MFMA-fragment-ordered bf16 (one-time) ----------------
// Wb[fi]: fi = (((kb5*NT + nt)*16 + c)*4 + kb)*8 + k7, where k = kb5*32+kb*8+k7,
// nn = nt*16 + c. Read in k_layer as a coalesced 1KB wave-load per (s,nt).
template <int DOUT>
__global__ void k_prepw(const float* __restrict__ Wl, const float* __restrict__ Wr,
                        unsigned short* __restrict__ Wb) {
  constexpr int NT = (DOUT + 15) / 16;
  constexpr int PADN = NT * 16;
  int fi = blockIdx.x * 256 + threadIdx.x;
  if (fi < 128 * PADN) {
    int k7 = fi & 7;
    int kb = (fi >> 3) & 3;
    int c16 = (fi >> 5) & 15;
    int rest = fi >> 9;          // kb5 * NT + nt
    int nt = rest % NT;
    int kb5 = rest / NT;
    int k = kb5 * 32 + kb * 8 + k7;
    int nn = nt * 16 + c16;
    float v = 0.f;
    if (nn < DOUT) v = (k < 64) ? Wl[k * DOUT + nn] : Wr[(k - 64) * DOUT + nn];
    Wb[fi] = (unsigned short)f2bf(v);
  }
}

// ---------------- fused SAGE layer: out = act([mean_agg(h), h] @ [Wl; Wr] + b) ----------------
// 4 waves/block, 16 rows/wave, NO cross-wave coupling (meanL is wave-private;
// W comes pre-packed from global). LDS = meanL only (10.2KB) -> 15 blocks/CU.
// Phase A: gather-mean (8 lanes/node, bf16 rows, 8 edges in flight).
// Phase B: MFMA K=128 (mean from LDS, own-row from global, W frags from global).
// mfma_f32_16x16x32_bf16: A row = lane&15, k = (lane>>4)*8+j; C/D col = lane&15,
// row = (lane>>4)*4 + reg  [verified R6-R12].
template <int DOUT, int ACT>
__global__ void __launch_bounds__(256) k_layer(const unsigned short* __restrict__ h,
                                               const int* __restrict__ row_ptr,
                                               const int* __restrict__ edge_src,
                                               const unsigned short* __restrict__ Wb,
                                               const float* __restrict__ bias,
                                               void* __restrict__ outv, int n) {
  constexpr int NT = (DOUT + 15) / 16;  // 4 (d=64) or 3 (d=40)
  __shared__ unsigned short meanL[4][16 * MPAD];
  int t = threadIdx.x;
  int w = t >> 6, lane = t & 63;
  int r0 = (blockIdx.x * 4 + w) * 16;  // wave's 16 rows
  int g = lane & 7;                    // dim-group of 8 bf16 (16B)

  // ---- phase A: gather-mean, two batches of 8 nodes, 8 edges in flight ----
  for (int half = 0; half < 2; ++half) {
    int node = half * 8 + (lane >> 3);
    int i = r0 + node;
    float a[8];
#pragma unroll
    for (int c = 0; c < 8; ++c) a[c] = 0.f;
    float scale = 0.f;
    if (i < n) {
      int rp0 = row_ptr[i], rp1 = row_ptr[i + 1];
      int deg = rp1 - rp0;
      scale = (deg > 0) ? (1.0f / (float)deg) : 0.f;
      for (int base = 0; base < deg; base += 8) {
        int idx = rp0 + base + g;
        int sv = (idx < rp1) ? edge_src[idx] : 0;  // 8 edges per node, coalesced
        int cnt = min(8, deg - base);
        uint4 v0, v1, v2, v3, v4, v5, v6, v7;
#pragma unroll
        for (int e = 0; e < 8; ++e) {
          int s = __shfl(sv, (lane & ~7) | e);
          const uint4* p = (const uint4*)(h + (size_t)s * 64) + g;
          if (e == 0 && e < cnt) v0 = *p;
          if (e == 1 && e < cnt) v1 = *p;
          if (e == 2 && e < cnt) v2 = *p;
          if (e == 3 && e < cnt) v3 = *p;
          if (e == 4 && e < cnt) v4 = *p;
          if (e == 5 && e < cnt) v5 = *p;
          if (e == 6 && e < cnt) v6 = *p;
          if (e == 7 && e < cnt) v7 = *p;
        }
#define ACCUM(vv, ee)                                                   \
        if ((ee) < cnt) {                                               \
          a[0] += bflo(vv.x); a[1] += bfhi(vv.x);                       \
          a[2] += bflo(vv.y); a[3] += bfhi(vv.y);                       \
          a[4] += bflo(vv.z); a[5] += bfhi(vv.z);                       \
          a[6] += bflo(vv.w); a[7] += bfhi(vv.w);                       \
        }
        ACCUM(v0, 0) ACCUM(v1, 1) ACCUM(v2, 2) ACCUM(v3, 3)
        ACCUM(v4, 4) ACCUM(v5, 5) ACCUM(v6, 6) ACCUM(v7, 7)
#undef ACCUM
      }
    }
    uint4 wv;
    wv.x = f2bf(a[0] * scale) | (f2bf(a[1] * scale) << 16);
    wv.y = f2bf(a[2] * scale) | (f2bf(a[3] * scale) << 16);
    wv.z = f2bf(a[4] * scale) | (f2bf(a[5] * scale) << 16);
    wv.w = f2bf(a[6] * scale) | (f2bf(a[7] * scale) << 16);
    *(uint4*)&meanL[w][node * MPAD + g * 8] = wv;
  }
  // meanL is wave-private: intra-wave LDS RAW needs only an LDS fence, no
  // block barrier -> waves proceed to MFMA independently (degree imbalance
  // no longer couples the whole block).
  __threadfence_block();

  // ---- phase B: MFMA ----
  int c = lane & 15;   // A row / C-D col
  int kb = lane >> 4;  // k-block of 8
  bf16x8 af[4];
  af[0] = *(const bf16x8*)&meanL[w][c * MPAD + kb * 8];        // mean, k 0..31
  af[1] = *(const bf16x8*)&meanL[w][c * MPAD + 32 + kb * 8];   // mean, k 32..63
  int row = r0 + c;
  if (row >= n) row = n - 1;  // clamp loads; stores guarded
  size_t rb = (size_t)row * 64 + kb * 8;
  af[2] = *(const bf16x8*)(h + rb);        // own row, k 0..31
  af[3] = *(const bf16x8*)(h + rb + 32);   // own row, k 32..63

  f32x4 acc[NT];
#pragma unroll
  for (int nt = 0; nt < NT; ++nt) acc[nt] = (f32x4){0.f, 0.f, 0.f, 0.f};
#pragma unroll
  for (int s = 0; s < 4; ++s) {
    bf16x8 bft[NT];  // load W frags per-s to cap register liveness
#pragma unroll
    for (int nt = 0; nt < NT; ++nt)
      bft[nt] = *(const bf16x8*)&Wb[(((s * NT + nt) * 16 + c) * 4 + kb) * 8];
#pragma unroll
    for (int nt = 0; nt < NT; ++nt)
      acc[nt] = __builtin_amdgcn_mfma_f32_16x16x32_bf16(af[s], bft[nt], acc[nt], 0, 0, 0);
  }

  int rbase = r0 + kb * 4;
  if (ACT == ACT_RELU) {
    unsigned short* out = (unsigned short*)outv;
#pragma unroll
    for (int nt = 0; nt < NT; ++nt) {
      float bval = bias[nt * 16 + c];
#pragma unroll
      for (int r = 0; r < 4; ++r) {
        int R = rbase + r;
        if (R < n) {
          float v = fmaxf(acc[nt][r] + bval, 0.f);
          out[(size_t)R * DOUT + nt * 16 + c] = (unsigned short)f2bf(v);
        }
      }
    }
  } else {
    float* out = (float*)outv;
    float bv[NT];
#pragma unroll
    for (int nt = 0; nt < NT; ++nt) bv[nt] = ((nt * 16 + c) < DOUT) ? bias[nt * 16 + c] : 0.f;
#pragma unroll
    for (int r = 0; r < 4; ++r) {
      int R = rbase + r;
      float v[NT];
      float m = -INFINITY;
#pragma unroll
      for (int nt = 0; nt < NT; ++nt) {
        bool valid = (nt * 16 + c) < DOUT;
        v[nt] = valid ? (acc[nt][r] + bv[nt]) : -INFINITY;
        m = fmaxf(m, v[nt]);
      }
#pragma unroll
      for (int off = 1; off < 16; off <<= 1) m = fmaxf(m, __shfl_xor(m, off));
      float es = 0.f;
#pragma unroll
      for (int nt = 0; nt < NT; ++nt)
        if ((nt * 16 + c) < DOUT) es += expf(v[nt] - m);
#pragma unroll
      for (int off = 1; off < 16; off <<= 1) es += __shfl_xor(es, off);
      float lse = logf(es);
      if (R < n) {
#pragma unroll
        for (int nt = 0; nt < NT; ++nt)
          if ((nt * 16 + c) < DOUT) out[(size_t)R * DOUT + nt * 16 + c] = v[nt] - m - lse;
      }
    }
  }
}

extern "C" void kernel_launch(void* const* d_in, const int* in_sizes, int n_in,
                              void* d_out, int out_size, void* d_ws, size_t ws_size,
                              hipStream_t stream) {
  const float* x   = (const float*)d_in[0];
  const int*   ei  = (const int*)d_in[1];
  const float* Wl0 = (const float*)d_in[2];
  const float* bl0 = (const float*)d_in[3];
  const float* Wr0 = (const float*)d_in[4];
  const float* Wl1 = (const float*)d_in[5];
  const float* bl1 = (const float*)d_in[6];
  const float* Wr1 = (const float*)d_in[7];
  const float* Wl2 = (const float*)d_in[8];
  const float* bl2 = (const float*)d_in[9];
  const float* Wr2 = (const float*)d_in[10];
  float* out = (float*)d_out;

  int N = in_sizes[0] / 64;
  int E = in_sizes[1] / 2;
  int M = N + 1;
  int NB = (N + 255) >> BSH;  // 391 for N=100000
  const int* src = ei;
  const int* dst = ei + E;

  char* p = (char*)d_ws;
  auto alloc = [&](size_t bytes) {
    char* r = p;
    p += (bytes + 255) & ~(size_t)255;
    return r;
  };
  int* cnt      = (int*)alloc((size_t)M * 4);
  int* row_ptr  = (int*)alloc((size_t)M * 4);
  int* cursor   = (int*)alloc((size_t)M * 4);
  int* bsum     = (int*)alloc(256 * 4);
  int* boff     = (int*)alloc(256 * 4);
  int* bk_cnt   = (int*)alloc((MAXNB + 1) * 4);
  int* bk_base  = (int*)alloc((MAXNB + 1) * 4);
  int* bk_cur   = (int*)alloc((MAXNB + 1) * 4);
  int* edge_src = (int*)alloc((size_t)E * 4);
  // R1: int2 tmp during CSR build, then xb (bf16 x), then hbB (layer-1 out)
  size_t szR1 = (size_t)E * 8 > (size_t)N * 128 ? (size_t)E * 8 : (size_t)N * 128;
  char* R1              = alloc(szR1);
  unsigned short* hbA   = (unsigned short*)alloc((size_t)N * 128);  // hidden (bf16)
  unsigned short* Wb0   = (unsigned short*)alloc(128 * 64 * 2);
  unsigned short* Wb1   = (unsigned short*)alloc(128 * 64 * 2);
  unsigned short* Wb2   = (unsigned short*)alloc(128 * 48 * 2);
  if ((size_t)(p - (char*)d_ws) > ws_size) return;  // ws too small: fail loudly

  bool bucketed = (NB <= MAXNB);
  int eb4 = (E + 4095) / 4096;

  // one-time weight pre-pack (fragment-ordered bf16)
  k_prepw<64><<<(128 * 64 + 255) / 256, 256, 0, stream>>>(Wl0, Wr0, Wb0);
  k_prepw<64><<<(128 * 64 + 255) / 256, 256, 0, stream>>>(Wl1, Wr1, Wb1);
  k_prepw<40><<<(128 * 48 + 255) / 256, 256, 0, stream>>>(Wl2, Wr2, Wb2);

  if (bucketed) {
    k_zero<<<(MAXNB + 256) / 256, 256, 0, stream>>>(bk_cnt, MAXNB + 1);
    k_histB<<<eb4, 256, 0, stream>>>(dst, bk_cnt, E, NB);
    k_bscan<<<1, MAXNB, 0, stream>>>(bk_cnt, bk_base, bk_cur, NB);
    k_partition<<<eb4, 256, 0, stream>>>(src, dst, bk_cur, (int2*)R1, E, NB);
    k_bmake<<<NB, 256, 0, stream>>>((const int2*)R1, bk_base, row_ptr, edge_src, N, E, NB);
  } else {
    k_zero<<<(M + 255) / 256, 256, 0, stream>>>(cnt, M);
    k_hist<<<(E + 255) / 256, 256, 0, stream>>>(dst, cnt, E);
    int nb = (M + 2047) / 2048;
    k_scan_part<<<nb, 256, 0, stream>>>(cnt, bsum, M);
    k_scan_mid<<<1, 64, 0, stream>>>(bsum, boff, nb);
    k_scan_final<<<nb, 256, 0, stream>>>(cnt, boff, row_ptr, cursor, M);
    k_fill<<<(E + 255) / 256, 256, 0, stream>>>(src, dst, cursor, edge_src, E);
  }

  unsigned short* xb  = (unsigned short*)R1;  // reuses tmp region (dead after k_bmake)
  unsigned short* hbB = (unsigned short*)R1;  // reused again (xb dead after layer 0)

  int cb = (N * 64 / 8 + 255) / 256;
  int gb = (N + 63) / 64;

  k_cast<<<cb, 256, 0, stream>>>(x, xb, N * 64);
  // layer 0: hbA = relu([mean_agg(xb), xb] @ [Wl0; Wr0] + bl0)
  k_layer<64, ACT_RELU><<<gb, 256, 0, stream>>>(xb, row_ptr, edge_src, Wb0, bl0, hbA, N);
  // layer 1: hbB = relu([mean_agg(hbA), hbA] @ [Wl1; Wr1] + bl1)
  k_layer<64, ACT_RELU><<<gb, 256, 0, stream>>>(hbA, row_ptr, edge_src, Wb1, bl1, hbB, N);
  // layer 2: out = log_softmax([mean_agg(hbB), hbB] @ [Wl2; Wr2] + bl2)
  k_layer<40, ACT_LSM><<<gb, 256, 0, stream>>>(hbB, row_ptr, edge_src, Wb2, bl2, out, N);
}